// Round 11
// baseline (1516.446 us; speedup 1.0000x reference)
//
#include <hip/hip_runtime.h>
#include <math.h>

// MS-SSIM loss, 5 levels, 11-tap separable Gaussian (sigma=1.5), VALID padding.
// Round 11: round-8 structure (best: 2 rows/iter, double-buffered LDS slot,
// 12-slot shift ring, 1 barrier/iter) with
//  - packed-f32 math: ext_vector_type(2) + __builtin_elementwise_fma so the
//    conv core compiles to v_pk_fma_f32/v_pk_mul_f32 (half the VALU instrs)
//  - smaller strips (L0 rps=32, rest 16): 2x blocks for latency hiding
//  - __launch_bounds__(256,8): pin VGPR <= 64 (occupancy cliff at 64, r10 lesson)
//  - per-wave atomic reduce (no final block barrier)
// 4-map transform (a=x+y, b=x-y -> P,Q,U,V), x2-rescaled emit algebra (exact).

typedef float f32x2 __attribute__((ext_vector_type(2)));

#define RWF 272          // staged float-cols per row: 256 band + 10 halo + pad

struct GWin { float w[11]; };

__global__ __launch_bounds__(256, 8)
void ssim_rows_kernel(const float* __restrict__ X, const float* __restrict__ Y,
                      float* __restrict__ poolX, float* __restrict__ poolY,
                      float* __restrict__ accum,   // [0..95]=ssim, [96..191]=cs
                      int S, int outS, int doPool, int rps, GWin gw)
{
    __shared__ f32x2 ab[2][2][RWF];      // [slot][row01][floatcol pair] = {a, b}

    const int ch  = blockIdx.z;
    const int oy0 = blockIdx.x * rps;
    const int cb0 = blockIdx.y * 256;
    const int tid = threadIdx.x;
    const int halfS = S >> 1;

    int rowsOut = outS - oy0; if (rowsOut > rps) rowsOut = rps;
    const int NIT = (rowsOut + 11) >> 1;     // iterations, 2 input rows each

    const float* Xc = X + (size_t)ch * S * S;
    const float* Yc = Y + (size_t)ch * S * S;

    // staging decode: 272 float2-col tasks over 2 rows (136 per row)
    const int  r0_ = (tid < 136) ? 0 : 1;
    const int  c20 = (tid < 136) ? tid : tid - 136;
    const bool hasT1 = (tid < 16);
    const int  c21 = 120 + tid;          // extra task: row 1, c2 in [120,136)

    f32x2 sx0, sy0, sx1, sy1;            // prefetched global data

    auto issue = [&](int baseRow) {      // load rows baseRow, baseRow+1 -> regs
        {
            int gr = baseRow + r0_; if (gr > S - 1) gr = S - 1;
            const float* xr = Xc + (size_t)gr * S;
            const float* yr = Yc + (size_t)gr * S;
            int gc = cb0 + 2 * c20;
            if (gc + 1 < S) {
                sx0 = *reinterpret_cast<const f32x2*>(xr + gc);
                sy0 = *reinterpret_cast<const f32x2*>(yr + gc);
            } else {
                int g0 = gc < S ? gc : S - 1;
                sx0.x = xr[g0]; sx0.y = xr[S - 1];
                sy0.x = yr[g0]; sy0.y = yr[S - 1];
            }
        }
        if (hasT1) {
            int gr = baseRow + 1; if (gr > S - 1) gr = S - 1;
            const float* xr = Xc + (size_t)gr * S;
            const float* yr = Yc + (size_t)gr * S;
            int gc = cb0 + 2 * c21;
            if (gc + 1 < S) {
                sx1 = *reinterpret_cast<const f32x2*>(xr + gc);
                sy1 = *reinterpret_cast<const f32x2*>(yr + gc);
            } else {
                int g0 = gc < S ? gc : S - 1;
                sx1.x = xr[g0]; sx1.y = xr[S - 1];
                sy1.x = yr[g0]; sy1.y = yr[S - 1];
            }
        }
    };
    auto write_slot = [&](int sl) {      // regs -> LDS interleaved {a,b}: one b128 per task
        float4 v0;
        v0.x = sx0.x + sy0.x; v0.y = sx0.x - sy0.x;
        v0.z = sx0.y + sy0.y; v0.w = sx0.y - sy0.y;
        *reinterpret_cast<float4*>(&ab[sl][r0_][2 * c20]) = v0;
        if (hasT1) {
            float4 v1;
            v1.x = sx1.x + sy1.x; v1.y = sx1.x - sy1.x;
            v1.z = sx1.y + sy1.y; v1.w = sx1.y - sy1.y;
            *reinterpret_cast<float4*>(&ab[sl][1][2 * c21]) = v1;
        }
    };

    // pending v-conv partials: 12 slots x {P,Q} + {U,V}, packed
    f32x2 pendPQ[12], pendUV[12];
    #pragma unroll
    for (int i = 0; i < 12; ++i) { pendPQ[i] = (f32x2){0.f, 0.f}; pendUV[i] = (f32x2){0.f, 0.f}; }

    float ssum = 0.f, csum = 0.f;
    const float C1x2 = 2e-4f, C2x2 = 1.8e-3f;
    const bool colOK = (cb0 + tid) < outS;

    // prologue
    issue(oy0);
    write_slot(0);
    issue(oy0 + 2);
    __syncthreads();

    for (int k = 0; k < NIT; ++k) {
        const int sl = k & 1;
        if (k + 1 < NIT) {
            write_slot(sl ^ 1);          // rows oy0+2(k+1) (regs from iter k-1)
            if (k + 2 < NIT) issue(oy0 + 2 * (k + 2));
        }

        // ---- h-conv for the 2 staged rows: 1 ds_read_b64 + 3 pk ops per tap ----
        f32x2 hPQ0 = {0.f, 0.f}, hUV0 = {0.f, 0.f};
        f32x2 hPQ1 = {0.f, 0.f}, hUV1 = {0.f, 0.f};
        #pragma unroll
        for (int t = 0; t < 11; ++t) {
            f32x2 ws = {gw.w[t], gw.w[t]};
            f32x2 v = ab[sl][0][tid + t];
            hPQ0 = __builtin_elementwise_fma(ws, v, hPQ0);
            hUV0 = __builtin_elementwise_fma(ws * v, v, hUV0);
        }
        #pragma unroll
        for (int t = 0; t < 11; ++t) {
            f32x2 ws = {gw.w[t], gw.w[t]};
            f32x2 v = ab[sl][1][tid + t];
            hPQ1 = __builtin_elementwise_fma(ws, v, hPQ1);
            hUV1 = __builtin_elementwise_fma(ws * v, v, hUV1);
        }

        // ---- v-accumulate into pending ring: 2 pk_fma per slot ----
        #pragma unroll
        for (int j = 0; j <= 10; ++j) {          // row 2k: w[10-j] -> slot j
            f32x2 ws = {gw.w[10 - j], gw.w[10 - j]};
            pendPQ[j] = __builtin_elementwise_fma(ws, hPQ0, pendPQ[j]);
            pendUV[j] = __builtin_elementwise_fma(ws, hUV0, pendUV[j]);
        }
        #pragma unroll
        for (int j = 1; j <= 11; ++j) {          // row 2k+1: w[11-j] -> slot j
            f32x2 ws = {gw.w[11 - j], gw.w[11 - j]};
            pendPQ[j] = __builtin_elementwise_fma(ws, hPQ1, pendPQ[j]);
            pendUV[j] = __builtin_elementwise_fma(ws, hUV1, pendUV[j]);
        }

        // ---- emit 2 finished output rows (x2-rescaled algebra, exact) ----
        #pragma unroll
        for (int e = 0; e < 2; ++e) {
            int rel = 2 * k - 10 + e;
            float p = pendPQ[e].x, q = pendPQ[e].y;
            float u = pendUV[e].x, v = pendUV[e].y;
            float p2 = p * p, q2 = q * q;
            float A = p2 - q2;                         // 2*(2 mu12)
            float csn = (u - v - A) + C2x2;            // 2*(2 sigma12) + 2C2
            float csd = (u + v - p2 - q2) + C2x2;
            float cs  = csn * __builtin_amdgcn_rcpf(csd);
            float ss  = (A + C1x2) * __builtin_amdgcn_rcpf(p2 + q2 + C1x2) * cs;
            if ((unsigned)rel < (unsigned)rowsOut && colOK) { ssum += ss; csum += cs; }
        }

        // ---- shift ring by 2 slots ----
        #pragma unroll
        for (int j = 0; j < 10; ++j) { pendPQ[j] = pendPQ[j + 2]; pendUV[j] = pendUV[j + 2]; }
        pendPQ[10] = (f32x2){0.f, 0.f}; pendUV[10] = (f32x2){0.f, 0.f};
        pendPQ[11] = (f32x2){0.f, 0.f}; pendUV[11] = (f32x2){0.f, 0.f};

        // ---- 2x2 pool of the 2 staged rows ----
        if (doPool && tid < 128 && k < (rps >> 1)) {
            float4 q0 = *reinterpret_cast<const float4*>(&ab[sl][0][2 * tid]);
            float4 q1 = *reinterpret_cast<const float4*>(&ab[sl][1][2 * tid]);
            float sa = q0.x + q0.z + q1.x + q1.z;
            float sb = q0.y + q0.w + q1.y + q1.w;
            int pc = (cb0 >> 1) + tid;
            if (pc < halfS) {
                int prow = (oy0 >> 1) + k;
                size_t o = (size_t)ch * halfS * halfS + (size_t)prow * halfS + pc;
                poolX[o] = 0.125f * (sa + sb);
                poolY[o] = 0.125f * (sa - sb);
            }
        }

        __syncthreads();
    }

    // ---- per-wave reduction + atomic accumulate ----
    for (int off = 32; off > 0; off >>= 1) {
        ssum += __shfl_down(ssum, off);
        csum += __shfl_down(csum, off);
    }
    if ((tid & 63) == 0) {
        atomicAdd(&accum[ch], ssum);
        atomicAdd(&accum[96 + ch], csum);
    }
}

__global__ void finalize_kernel(const float* __restrict__ accum, float* __restrict__ out)
{
    __shared__ float red[2];
    const int t = threadIdx.x;   // 128 threads
    const float w[5]   = {0.0448f, 0.2856f, 0.3001f, 0.2363f, 0.1333f};
    const float inv[5] = {1.f / (502.f * 502.f), 1.f / (246.f * 246.f),
                          1.f / (118.f * 118.f), 1.f / (54.f * 54.f),
                          1.f / (22.f * 22.f)};
    float ms = 0.f;
    if (t < 96) {
        ms = 1.f;
        #pragma unroll
        for (int l = 0; l < 5; ++l) {
            float v = (l < 4) ? accum[l * 192 + 96 + t] : accum[l * 192 + t];
            v *= inv[l];
            v = fmaxf(v, 0.f);
            ms *= powf(v, w[l]);
        }
    }
    for (int off = 32; off > 0; off >>= 1) ms += __shfl_down(ms, off);
    int wid = t >> 6, lane = t & 63;
    if (lane == 0) red[wid] = ms;
    __syncthreads();
    if (t == 0) out[0] = 1.f - (red[0] + red[1]) * (1.f / 96.f);
}

extern "C" void kernel_launch(void* const* d_in, const int* in_sizes, int n_in,
                              void* d_out, int out_size, void* d_ws, size_t ws_size,
                              hipStream_t stream)
{
    (void)in_sizes; (void)n_in; (void)out_size; (void)ws_size;
    const float* X = (const float*)d_in[0];
    const float* Y = (const float*)d_in[1];
    float* out = (float*)d_out;
    float* ws  = (float*)d_ws;

    // Gaussian window (size 11, sigma 1.5), normalized
    GWin gw;
    {
        double g[11], s = 0.0;
        for (int i = 0; i < 11; ++i) { double d = i - 5; g[i] = exp(-(d * d) / 4.5); s += g[i]; }
        for (int i = 0; i < 11; ++i) gw.w[i] = (float)(g[i] / s);
    }

    // workspace layout (floats)
    float* accum = ws;                 // 5 levels * 192
    size_t off = 1024;
    float* p1x = ws + off; off += (size_t)96 * 256 * 256;
    float* p1y = ws + off; off += (size_t)96 * 256 * 256;
    float* p2x = ws + off; off += (size_t)96 * 128 * 128;
    float* p2y = ws + off; off += (size_t)96 * 128 * 128;
    float* p3x = ws + off; off += (size_t)96 * 64 * 64;
    float* p3y = ws + off; off += (size_t)96 * 64 * 64;
    float* p4x = ws + off; off += (size_t)96 * 32 * 32;
    float* p4y = ws + off; off += (size_t)96 * 32 * 32;

    hipMemsetAsync(accum, 0, 5 * 192 * sizeof(float), stream);

    auto launch = [&](const float* x, const float* y, float* px_, float* py_,
                      float* acc, int S, int outS, int pool) {
        int rps = (S >= 512) ? 32 : 16;               // output rows per block
        dim3 g((outS + rps - 1) / rps, (S + 255) / 256, 96);
        ssim_rows_kernel<<<g, 256, 0, stream>>>(x, y, px_, py_, acc, S, outS, pool, rps, gw);
    };

    launch(X,   Y,   p1x, p1y, accum + 0,   512, 502, 1);
    launch(p1x, p1y, p2x, p2y, accum + 192, 256, 246, 1);
    launch(p2x, p2y, p3x, p3y, accum + 384, 128, 118, 1);
    launch(p3x, p3y, p4x, p4y, accum + 576, 64,  54,  1);
    launch(p4x, p4y, nullptr, nullptr, accum + 768, 32, 22, 0);

    finalize_kernel<<<1, 128, 0, stream>>>(accum, out);
}

// Round 12
// 234.974 us; speedup vs baseline: 6.4537x; 6.4537x over previous
//
#include <hip/hip_runtime.h>
#include <math.h>

// MS-SSIM loss, 5 levels, 11-tap separable Gaussian (sigma=1.5), VALID padding.
// Round 12: round-8 structure EXACTLY (best so far: 2 rows/iter, double-buffered
// LDS slot, 12-slot shift ring, 1 barrier/iter, natural ~64 VGPR — NO min-wave
// launch bound, r11 lesson: forcing 8 waves/EU spilled everything to scratch)
// + packed-f32 conv math via ext_vector_type(2) / __builtin_elementwise_fma
//   (v_pk_fma_f32: halves VALU instruction count)
// + rowsOut-trimmed iteration count for tail strips
// + per-wave atomic reduce (no final block barrier).
// 4-map transform (a=x+y, b=x-y -> P,Q,U,V), x2-rescaled emit algebra (exact).

typedef float f32x2 __attribute__((ext_vector_type(2)));

#define RWF 272          // staged float-cols per row: 256 band + 10 halo + pad

struct GWin { float w[11]; };

__global__ __launch_bounds__(256)
void ssim_rows_kernel(const float* __restrict__ X, const float* __restrict__ Y,
                      float* __restrict__ poolX, float* __restrict__ poolY,
                      float* __restrict__ accum,   // [0..95]=ssim, [96..191]=cs
                      int S, int outS, int doPool, int rps, GWin gw)
{
    __shared__ f32x2 ab[2][2][RWF];      // [slot][row01][floatcol] = {a, b}

    const int ch  = blockIdx.z;
    const int oy0 = blockIdx.x * rps;
    const int cb0 = blockIdx.y * 256;
    const int tid = threadIdx.x;
    const int halfS = S >> 1;

    int rowsOut = outS - oy0; if (rowsOut > rps) rowsOut = rps;
    const int NIT = (rowsOut + 11) >> 1;     // iterations (2 input rows each)

    const float* Xc = X + (size_t)ch * S * S;
    const float* Yc = Y + (size_t)ch * S * S;

    // staging task decode: 272 float2-col tasks over 2 rows (136 per row)
    const int  r0_ = (tid < 136) ? 0 : 1;
    const int  c20 = (tid < 136) ? tid : tid - 136;
    const bool hasT1 = (tid < 16);
    const int  c21 = 120 + tid;          // extra task: row 1, c2 in [120,136)

    f32x2 sx0, sy0, sx1, sy1;            // prefetched global data

    auto issue = [&](int baseRow) {      // load rows baseRow, baseRow+1 -> regs
        {
            int gr = baseRow + r0_; if (gr > S - 1) gr = S - 1;
            const float* xr = Xc + (size_t)gr * S;
            const float* yr = Yc + (size_t)gr * S;
            int gc = cb0 + 2 * c20;
            if (gc + 1 < S) {
                sx0 = *reinterpret_cast<const f32x2*>(xr + gc);
                sy0 = *reinterpret_cast<const f32x2*>(yr + gc);
            } else {
                int g0 = gc < S ? gc : S - 1;
                sx0.x = xr[g0]; sx0.y = xr[S - 1];
                sy0.x = yr[g0]; sy0.y = yr[S - 1];
            }
        }
        if (hasT1) {
            int gr = baseRow + 1; if (gr > S - 1) gr = S - 1;
            const float* xr = Xc + (size_t)gr * S;
            const float* yr = Yc + (size_t)gr * S;
            int gc = cb0 + 2 * c21;
            if (gc + 1 < S) {
                sx1 = *reinterpret_cast<const f32x2*>(xr + gc);
                sy1 = *reinterpret_cast<const f32x2*>(yr + gc);
            } else {
                int g0 = gc < S ? gc : S - 1;
                sx1.x = xr[g0]; sx1.y = xr[S - 1];
                sy1.x = yr[g0]; sy1.y = yr[S - 1];
            }
        }
    };
    auto write_slot = [&](int sl) {      // regs -> LDS interleaved {a,b}: one b128 per task
        float4 v0;
        v0.x = sx0.x + sy0.x; v0.y = sx0.x - sy0.x;
        v0.z = sx0.y + sy0.y; v0.w = sx0.y - sy0.y;
        *reinterpret_cast<float4*>(&ab[sl][r0_][2 * c20]) = v0;
        if (hasT1) {
            float4 v1;
            v1.x = sx1.x + sy1.x; v1.y = sx1.x - sy1.x;
            v1.z = sx1.y + sy1.y; v1.w = sx1.y - sy1.y;
            *reinterpret_cast<float4*>(&ab[sl][1][2 * c21]) = v1;
        }
    };

    // pending v-conv partials: 12 slots x {P,Q} + {U,V}, packed
    f32x2 pendPQ[12], pendUV[12];
    #pragma unroll
    for (int i = 0; i < 12; ++i) { pendPQ[i] = (f32x2){0.f, 0.f}; pendUV[i] = (f32x2){0.f, 0.f}; }

    float ssum = 0.f, csum = 0.f;
    const float C1x2 = 2e-4f, C2x2 = 1.8e-3f;
    const bool colOK = (cb0 + tid) < outS;

    // prologue
    issue(oy0);
    write_slot(0);
    issue(oy0 + 2);
    __syncthreads();

    for (int k = 0; k < NIT; ++k) {
        const int sl = k & 1;
        if (k + 1 < NIT) {
            write_slot(sl ^ 1);          // rows oy0+2(k+1) (regs from iter k-1)
            if (k + 3 <= NIT) issue(oy0 + 2 * (k + 2));
        }

        // ---- h-conv for the 2 staged rows: 1 ds_read_b64 + 3 pk ops per tap ----
        f32x2 hPQ0 = {0.f, 0.f}, hUV0 = {0.f, 0.f};
        f32x2 hPQ1 = {0.f, 0.f}, hUV1 = {0.f, 0.f};
        #pragma unroll
        for (int t = 0; t < 11; ++t) {
            float wt = gw.w[t];
            f32x2 ws = {wt, wt};
            f32x2 v = ab[sl][0][tid + t];
            hPQ0 = __builtin_elementwise_fma(ws, v, hPQ0);
            hUV0 = __builtin_elementwise_fma(ws * v, v, hUV0);
        }
        #pragma unroll
        for (int t = 0; t < 11; ++t) {
            float wt = gw.w[t];
            f32x2 ws = {wt, wt};
            f32x2 v = ab[sl][1][tid + t];
            hPQ1 = __builtin_elementwise_fma(ws, v, hPQ1);
            hUV1 = __builtin_elementwise_fma(ws * v, v, hUV1);
        }

        // ---- v-accumulate into pending ring: 2 pk_fma per slot ----
        #pragma unroll
        for (int j = 0; j <= 10; ++j) {          // row 2k: w[10-j] -> slot j
            float wt = gw.w[10 - j];
            f32x2 ws = {wt, wt};
            pendPQ[j] = __builtin_elementwise_fma(ws, hPQ0, pendPQ[j]);
            pendUV[j] = __builtin_elementwise_fma(ws, hUV0, pendUV[j]);
        }
        #pragma unroll
        for (int j = 1; j <= 11; ++j) {          // row 2k+1: w[11-j] -> slot j
            float wt = gw.w[11 - j];
            f32x2 ws = {wt, wt};
            pendPQ[j] = __builtin_elementwise_fma(ws, hPQ1, pendPQ[j]);
            pendUV[j] = __builtin_elementwise_fma(ws, hUV1, pendUV[j]);
        }

        // ---- emit 2 finished output rows (x2-rescaled algebra, exact) ----
        #pragma unroll
        for (int e = 0; e < 2; ++e) {
            int rel = 2 * k - 10 + e;
            float p = pendPQ[e].x, q = pendPQ[e].y;
            float u = pendUV[e].x, v = pendUV[e].y;
            float p2 = p * p, q2 = q * q;
            float A = p2 - q2;                         // 2*(2 mu12)
            float csn = (u - v - A) + C2x2;            // 2*(2 sigma12) + 2C2
            float csd = (u + v - p2 - q2) + C2x2;
            float cs  = csn * __builtin_amdgcn_rcpf(csd);
            float ss  = (A + C1x2) * __builtin_amdgcn_rcpf(p2 + q2 + C1x2) * cs;
            if ((unsigned)rel < (unsigned)rowsOut && colOK) { ssum += ss; csum += cs; }
        }

        // ---- shift ring by 2 slots ----
        #pragma unroll
        for (int j = 0; j < 10; ++j) { pendPQ[j] = pendPQ[j + 2]; pendUV[j] = pendUV[j + 2]; }
        pendPQ[10] = (f32x2){0.f, 0.f}; pendUV[10] = (f32x2){0.f, 0.f};
        pendPQ[11] = (f32x2){0.f, 0.f}; pendUV[11] = (f32x2){0.f, 0.f};

        // ---- 2x2 pool of the 2 staged rows ----
        if (doPool && tid < 128 && k < (rps >> 1)) {
            float4 q0 = *reinterpret_cast<const float4*>(&ab[sl][0][2 * tid]);
            float4 q1 = *reinterpret_cast<const float4*>(&ab[sl][1][2 * tid]);
            float sa = q0.x + q0.z + q1.x + q1.z;
            float sb = q0.y + q0.w + q1.y + q1.w;
            int pc = (cb0 >> 1) + tid;
            if (pc < halfS) {
                int prow = (oy0 >> 1) + k;
                size_t o = (size_t)ch * halfS * halfS + (size_t)prow * halfS + pc;
                poolX[o] = 0.125f * (sa + sb);
                poolY[o] = 0.125f * (sa - sb);
            }
        }

        __syncthreads();
    }

    // ---- per-wave reduction + atomic accumulate ----
    for (int off = 32; off > 0; off >>= 1) {
        ssum += __shfl_down(ssum, off);
        csum += __shfl_down(csum, off);
    }
    if ((tid & 63) == 0) {
        atomicAdd(&accum[ch], ssum);
        atomicAdd(&accum[96 + ch], csum);
    }
}

__global__ void finalize_kernel(const float* __restrict__ accum, float* __restrict__ out)
{
    __shared__ float red[2];
    const int t = threadIdx.x;   // 128 threads
    const float w[5]   = {0.0448f, 0.2856f, 0.3001f, 0.2363f, 0.1333f};
    const float inv[5] = {1.f / (502.f * 502.f), 1.f / (246.f * 246.f),
                          1.f / (118.f * 118.f), 1.f / (54.f * 54.f),
                          1.f / (22.f * 22.f)};
    float ms = 0.f;
    if (t < 96) {
        ms = 1.f;
        #pragma unroll
        for (int l = 0; l < 5; ++l) {
            float v = (l < 4) ? accum[l * 192 + 96 + t] : accum[l * 192 + t];
            v *= inv[l];
            v = fmaxf(v, 0.f);
            ms *= powf(v, w[l]);
        }
    }
    for (int off = 32; off > 0; off >>= 1) ms += __shfl_down(ms, off);
    int wid = t >> 6, lane = t & 63;
    if (lane == 0) red[wid] = ms;
    __syncthreads();
    if (t == 0) out[0] = 1.f - (red[0] + red[1]) * (1.f / 96.f);
}

extern "C" void kernel_launch(void* const* d_in, const int* in_sizes, int n_in,
                              void* d_out, int out_size, void* d_ws, size_t ws_size,
                              hipStream_t stream)
{
    (void)in_sizes; (void)n_in; (void)out_size; (void)ws_size;
    const float* X = (const float*)d_in[0];
    const float* Y = (const float*)d_in[1];
    float* out = (float*)d_out;
    float* ws  = (float*)d_ws;

    // Gaussian window (size 11, sigma 1.5), normalized
    GWin gw;
    {
        double g[11], s = 0.0;
        for (int i = 0; i < 11; ++i) { double d = i - 5; g[i] = exp(-(d * d) / 4.5); s += g[i]; }
        for (int i = 0; i < 11; ++i) gw.w[i] = (float)(g[i] / s);
    }

    // workspace layout (floats)
    float* accum = ws;                 // 5 levels * 192
    size_t off = 1024;
    float* p1x = ws + off; off += (size_t)96 * 256 * 256;
    float* p1y = ws + off; off += (size_t)96 * 256 * 256;
    float* p2x = ws + off; off += (size_t)96 * 128 * 128;
    float* p2y = ws + off; off += (size_t)96 * 128 * 128;
    float* p3x = ws + off; off += (size_t)96 * 64 * 64;
    float* p3y = ws + off; off += (size_t)96 * 64 * 64;
    float* p4x = ws + off; off += (size_t)96 * 32 * 32;
    float* p4y = ws + off; off += (size_t)96 * 32 * 32;

    hipMemsetAsync(accum, 0, 5 * 192 * sizeof(float), stream);

    auto launch = [&](const float* x, const float* y, float* px_, float* py_,
                      float* acc, int S, int outS, int pool) {
        int rps = (S >= 512) ? 64 : 32;               // output rows per block
        dim3 g((outS + rps - 1) / rps, (S + 255) / 256, 96);
        ssim_rows_kernel<<<g, 256, 0, stream>>>(x, y, px_, py_, acc, S, outS, pool, rps, gw);
    };

    launch(X,   Y,   p1x, p1y, accum + 0,   512, 502, 1);
    launch(p1x, p1y, p2x, p2y, accum + 192, 256, 246, 1);
    launch(p2x, p2y, p3x, p3y, accum + 384, 128, 118, 1);
    launch(p3x, p3y, p4x, p4y, accum + 576, 64,  54,  1);
    launch(p4x, p4y, nullptr, nullptr, accum + 768, 32, 22, 0);

    finalize_kernel<<<1, 128, 0, stream>>>(accum, out);
}